// Round 1
// 412.456 us; speedup vs baseline: 1.0400x; 1.0400x over previous
//
#include <hip/hip_runtime.h>

// Problem: B=16, N=128, F=64, K=128, C=3 (all fp32)
//   pa = S @ w[:F]  (+ b)     -> (B*N, K)
//   pb = S @ w[F:]            -> (B*N, K)
//   out[b,i,j,c,k] = (pa[b,i,k] + pb[b,j,k]) * dist[b,i,j,c]
// out = 402.65 MB fp32 -> HBM-write-bound. Target ~64-70 us write roofline
// for the controllable portion.

#define BN   2048      // B*N rows
#define FF   64        // F
#define KK   128       // K

typedef float f4 __attribute__((ext_vector_type(4)));

// Kernel A: per-row mini-GEMM. One block per row r (b*N+i), 128 threads = one k each.
// pa gets bias folded in. W columns (stride-128) are coalesced across k-threads;
// W (64 KB) is L2-resident after first block. (~5-10 us, unchanged from verified version.)
__global__ __launch_bounds__(128) void proj_kernel(
    const float* __restrict__ S,   // (BN, F)
    const float* __restrict__ W,   // (2F, K)
    const float* __restrict__ bias,// (K,)
    float* __restrict__ pa,        // (BN, K)  = S@W[:F] + bias
    float* __restrict__ pb)        // (BN, K)  = S@W[F:]
{
    __shared__ float s[FF];
    const int r = blockIdx.x;
    const int k = threadIdx.x;
    if (k < FF) s[k] = S[r * FF + k];
    __syncthreads();

    float acc_a = bias[k];
    float acc_b = 0.0f;
#pragma unroll
    for (int f = 0; f < FF; ++f) {
        const float sv = s[f];                 // LDS broadcast, conflict-free
        acc_a = fmaf(sv, W[f * KK + k], acc_a);
        acc_b = fmaf(sv, W[(f + FF) * KK + k], acc_b);
    }
    pa[r * KK + k] = acc_a;
    pb[r * KK + k] = acc_b;
}

// Kernel B: expansion, restructured to a pure streaming-store loop.
// One block per (b,i) = 2048 blocks, 384 threads (6 waves).
// Flat float4 index f = it*384 + t, it = 0..31. Since 384 = 4*96:
//   j  = it*4 + t/96      (t/96 loop-invariant)
//   c  = (t%96)>>5        (loop-invariant)
//   kq = (t%96)&31        (loop-invariant)
// -> no division in the loop; pa fragment is a loop-invariant register float4;
//    dist comes from a 1.5 KB LDS stage (broadcast, conflict-free);
//    pb read marches at a constant 2 KB stride (L2-resident);
//    out stores are contiguous 16 B/lane, non-temporal (out is never re-read).
__global__ __launch_bounds__(384) void expand_kernel(
    const float* __restrict__ dist,  // (B, N, N, C)
    const float* __restrict__ pa,    // (BN, K) incl. bias
    const float* __restrict__ pb,    // (BN, K)
    float* __restrict__ out)         // (B, N, N, C, K)
{
    const int bi = blockIdx.x;          // b*128 + i
    const int b  = bi >> 7;
    const int t  = threadIdx.x;         // 0..383

    const int jt = t / 96;              // 0..3   (compile-time-ish: uniform per 96-thread slab)
    const int rr = t - jt * 96;         // 0..95
    const int c  = rr >> 5;             // 0..2
    const int kq = rr & 31;             // 0..31

    // Stage dist[bi, :, :] (128*3 floats) into LDS. One float per thread, coalesced.
    __shared__ float dls[384];
    dls[t] = dist[(size_t)bi * 384 + t];

    // pa fragment for this thread's k-quad: loop-invariant, broadcast within 32-lane cluster.
    const f4 p = ((const f4*)pa)[bi * (KK / 4) + kq];
    __syncthreads();

    // pb base for (j = jt, kq); j advances by 4 per iteration -> +128 float4.
    const f4* __restrict__ pb_p = (const f4*)pb + ((size_t)b * 128) * (KK / 4) + jt * (KK / 4) + kq;
    // dist LDS base for (j = jt, c); j advances by 4 -> +12 floats.
    const float* __restrict__ dp = &dls[jt * 3 + c];
    // out base: f = it*384 + t.
    f4* __restrict__ out_p = (f4*)out + (size_t)bi * 12288 + t;

#pragma unroll 8
    for (int it = 0; it < 32; ++it) {
        const f4    q = pb_p[it * 128];
        const float d = dp[it * 12];
        f4 o;
        o.x = (p.x + q.x) * d;
        o.y = (p.y + q.y) * d;
        o.z = (p.z + q.z) * d;
        o.w = (p.w + q.w) * d;
        __builtin_nontemporal_store(o, out_p + it * 384);
    }
}

extern "C" void kernel_launch(void* const* d_in, const int* in_sizes, int n_in,
                              void* d_out, int out_size, void* d_ws, size_t ws_size,
                              hipStream_t stream) {
    const float* S    = (const float*)d_in[0];  // (16,128,64)
    const float* dist = (const float*)d_in[1];  // (16,128,128,3)
    const float* W    = (const float*)d_in[2];  // (128,128)
    const float* bias = (const float*)d_in[3];  // (128,)
    float* out = (float*)d_out;

    float* pa = (float*)d_ws;                   // BN*K floats = 1 MB
    float* pb = pa + (size_t)BN * KK;           // 1 MB

    proj_kernel<<<BN, 128, 0, stream>>>(S, W, bias, pa, pb);
    expand_kernel<<<BN, 384, 0, stream>>>(dist, pa, pb, out);
}